// Round 3
// baseline (13199.619 us; speedup 1.0000x reference)
//
#include <hip/hip_runtime.h>
#include <hip/hip_fp16.h>

// ---------------------------------------------------------------------------
// 2-layer LSTM (B=256, T=256, D=128, H=1024) + final Linear(H->128).
// Persistent kernel (plain launch, 256 blocks <= 256 CUs -> co-residency is
// capacity-guaranteed), one phase per timestep, custom device-scope grid
// barrier (bounded spin). fp16 MFMA (16x16x32) with fp32 accumulation.
// Phase t computes: gates1(t) = h_a(t)@W_ih1^T + h_b(t-1)@W_hh1^T  -> h_b(t)
//                   gates0(t+1) = x(t+1)@W_ih0^T + h_a(t)@W_hh0^T -> h_a(t+1)
// Cell states stay in registers for the whole kernel.
// ---------------------------------------------------------------------------

#define Bq 256
#define Tq 256
#define Dq 128
#define Hq 1024

typedef _Float16 half8 __attribute__((ext_vector_type(8)));
typedef float    floatx4 __attribute__((ext_vector_type(4)));

#define N_W1 8388608LL   // 64cg * 64ks * 4kb * 64col * 8e   (fp16 elems)
#define N_W0 4718592LL   // 64cg * 36ks * 4kb * 64col * 8e
#define N_XH 8388608LL   // T*B*D
#define N_H  262144LL    // B*H
#define BH   262144      // B*H

// ws byte offsets
#define OFF_W1 0LL
#define OFF_W0 16777216LL
#define OFF_XH 26214400LL
#define OFF_BA 42991616LL
#define OFF_BB 44040192LL
#define OFF_HF 45088768LL
#define OFF_SY 46137344LL
#define REQ_WS 46137472LL   // OFF_SY + 128

// ---------------------------------------------------------------------------
__global__ void ws_sentinel_kernel(float* __restrict__ out, int n, float v)
{
    int i = blockIdx.x * blockDim.x + threadIdx.x;
    if (i < n) out[i] = v;
}

// ---------------------------------------------------------------------------
__global__ void prep_kernel(const float* __restrict__ x, const float* __restrict__ h0,
                            const float* __restrict__ Wih0, const float* __restrict__ Whh0,
                            const float* __restrict__ Wih1, const float* __restrict__ Whh1,
                            _Float16* __restrict__ w1p, _Float16* __restrict__ w0p,
                            _Float16* __restrict__ xh,
                            _Float16* __restrict__ bufA, _Float16* __restrict__ bufB,
                            unsigned* __restrict__ sync)
{
    long long gid = (long long)blockIdx.x * blockDim.x + threadIdx.x;
    if (gid == 0) { sync[0] = 0u; sync[1] = 0u; }

    if (gid < N_W1) {
        // layout [cg][ks][kb][col][e]; col = g*16+jj -> weight row g*1024+cg*16+jj
        long long i = gid;
        int e  = (int)(i & 7);
        int c  = (int)((i >> 3) & 63);
        int kb = (int)((i >> 9) & 3);
        int ks = (int)((i >> 11) & 63);
        int cg = (int)(i >> 17);
        int row = (c >> 4) * 1024 + cg * 16 + (c & 15);
        int k = ks * 32 + kb * 8 + e;
        float v = (k < 1024) ? Wih1[(size_t)row * 1024 + k]
                             : Whh1[(size_t)row * 1024 + (k - 1024)];
        w1p[i] = (_Float16)v;
    } else if (gid < N_W1 + N_W0) {
        long long i = gid - N_W1;
        int cg = (int)(i / 73728LL);       // 36*4*64*8
        long long r = i % 73728LL;
        int ks = (int)(r >> 11);
        int kb = (int)((r >> 9) & 3);
        int c  = (int)((r >> 3) & 63);
        int e  = (int)(r & 7);
        int row = (c >> 4) * 1024 + cg * 16 + (c & 15);
        int k = ks * 32 + kb * 8 + e;
        float v = (k < 128) ? Wih0[(size_t)row * 128 + k]
                            : Whh0[(size_t)row * 1024 + (k - 128)];
        w0p[i] = (_Float16)v;
    } else if (gid < N_W1 + N_W0 + N_XH) {
        long long i = gid - N_W1 - N_W0;
        // xh[t][b][d] = x[b][t][d]
        int d = (int)(i & 127);
        int b = (int)((i >> 7) & 255);
        int t = (int)(i >> 15);
        xh[i] = (_Float16)x[((size_t)b * 256 + t) * 128 + d];
    } else if (gid < N_W1 + N_W0 + N_XH + N_H) {
        long long i = gid - N_W1 - N_W0 - N_XH;
        _Float16 v = (_Float16)h0[i];
        bufA[BH + i] = v;   // h_a(-1) parity 1
        bufB[BH + i] = v;   // h_b(-1) parity 1
    }
}

// ---------------------------------------------------------------------------
__device__ __forceinline__ void gridbar(unsigned* cnt, unsigned* gen, unsigned target)
{
    __syncthreads();
    if (threadIdx.x == 0) {
        unsigned prev = __hip_atomic_fetch_add(cnt, 1u, __ATOMIC_ACQ_REL,
                                               __HIP_MEMORY_SCOPE_AGENT);
        if (prev == gridDim.x - 1u) {
            __hip_atomic_store(cnt, 0u, __ATOMIC_RELAXED, __HIP_MEMORY_SCOPE_AGENT);
            __hip_atomic_store(gen, target, __ATOMIC_RELEASE, __HIP_MEMORY_SCOPE_AGENT);
        } else {
            // relaxed bounded spin; one acquire at exit. Bound (2^21 polls,
            // ~0.09 s) turns any barrier-logic bug into a fast wrong answer
            // instead of a wedged GPU/container.
            int guard = 0;
            while (__hip_atomic_load(gen, __ATOMIC_RELAXED, __HIP_MEMORY_SCOPE_AGENT) < target) {
                __builtin_amdgcn_s_sleep(1);
                if (++guard > (1 << 21)) break;
            }
            (void)__hip_atomic_load(gen, __ATOMIC_ACQUIRE, __HIP_MEMORY_SCOPE_AGENT);
        }
    }
    __syncthreads();
}

#define MFMA16(A, Bv, C) __builtin_amdgcn_mfma_f32_16x16x32_f16((A), (Bv), (C), 0, 0, 0)

#define KSTEP(AP0, AP1, BP) do {                                   \
    half8 a0 = *(const half8*)(AP0);                               \
    half8 a1 = *(const half8*)(AP1);                               \
    half8 b0 = *(const half8*)(BP);                                \
    half8 b1 = *(const half8*)((BP) + 128);                        \
    half8 b2 = *(const half8*)((BP) + 256);                        \
    half8 b3 = *(const half8*)((BP) + 384);                        \
    acc[0][0] = MFMA16(a0, b0, acc[0][0]);                         \
    acc[1][0] = MFMA16(a1, b0, acc[1][0]);                         \
    acc[0][1] = MFMA16(a0, b1, acc[0][1]);                         \
    acc[1][1] = MFMA16(a1, b1, acc[1][1]);                         \
    acc[0][2] = MFMA16(a0, b2, acc[0][2]);                         \
    acc[1][2] = MFMA16(a1, b2, acc[1][2]);                         \
    acc[0][3] = MFMA16(a0, b3, acc[0][3]);                         \
    acc[1][3] = MFMA16(a1, b3, acc[1][3]);                         \
} while (0)

__global__ void __launch_bounds__(256)
lstm_main(const _Float16* __restrict__ w1p, const _Float16* __restrict__ w0p,
          const _Float16* __restrict__ xh,
          _Float16* __restrict__ bufA, _Float16* __restrict__ bufB,
          float* __restrict__ hbF,
          const float* __restrict__ c0,
          const float* __restrict__ bih0, const float* __restrict__ bhh0,
          const float* __restrict__ bih1, const float* __restrict__ bhh1,
          const float* __restrict__ Wout, const float* __restrict__ bout,
          float* __restrict__ out, unsigned* __restrict__ sync)
{
    const int tid  = threadIdx.x;
    const int lane = tid & 63;
    const int w    = tid >> 6;                 // 0..3
    const int bid  = blockIdx.x;
    // XCD-grouping: the 4 btile-blocks of one colgroup land on one XCD (bid%8)
    const int cg = (bid & 7) * 8 + (bid >> 5);
    const int bt = (bid >> 3) & 3;
    const int jbase = cg * 16;
    const int jj = lane & 15;
    const int kb = lane >> 4;                  // 0..3
    const int isL1 = (w < 2) ? 1 : 0;
    const int rh = w & 1;
    const int rowbase = bt * 64 + rh * 32;     // wave's 32 rows

    unsigned* cnt = sync;
    unsigned* gen = sync + 1;

    floatx4 acc[2][4];
    float   cc[2][4];
    float   bias[4];
    {
        const float* bi = isL1 ? bih1 : bih0;
        const float* bh = isL1 ? bhh1 : bhh0;
#pragma unroll
        for (int g = 0; g < 4; ++g) {
            int col = g * 1024 + jbase + jj;
            bias[g] = bi[col] + bh[col];
        }
    }
#pragma unroll
    for (int mf = 0; mf < 2; ++mf)
#pragma unroll
        for (int r = 0; r < 4; ++r)
            cc[mf][r] = c0[(size_t)(rowbase + mf * 16 + kb * 4 + r) * Hq + jbase + jj];

    const _Float16* wseg1 = w1p + (size_t)cg * 131072 + kb * 512 + jj * 8;
    const _Float16* wseg0 = w0p + (size_t)cg * 73728  + kb * 512 + jj * 8;

    for (int t = -1; t <= 255; ++t) {
#pragma unroll
        for (int mf = 0; mf < 2; ++mf)
#pragma unroll
            for (int g = 0; g < 4; ++g)
                acc[mf][g] = (floatx4){0.f, 0.f, 0.f, 0.f};

        if (isL1) {
            if (t >= 0) {
                // gates1(t) = h_a(t)@Wih1^T + h_b(t-1)@Whh1^T
                const _Float16* ap = bufA + (size_t)(t & 1) * BH
                                   + (size_t)(rowbase + jj) * Hq + kb * 8;
                const _Float16* bp = wseg1;
#pragma unroll 2
                for (int ks = 0; ks < 32; ++ks) { KSTEP(ap, ap + 16 * Hq, bp); ap += 32; bp += 2048; }
                ap = bufB + (size_t)((t + 1) & 1) * BH
                   + (size_t)(rowbase + jj) * Hq + kb * 8;
#pragma unroll 2
                for (int ks = 0; ks < 32; ++ks) { KSTEP(ap, ap + 16 * Hq, bp); ap += 32; bp += 2048; }
            }
        } else {
            if (t < 255) {
                // gates0(t+1) = x(t+1)@Wih0^T + h_a(t)@Whh0^T
                const _Float16* ap = xh + (size_t)(t + 1) * (Bq * Dq)
                                   + (size_t)(rowbase + jj) * Dq + kb * 8;
                const _Float16* bp = wseg0;
#pragma unroll
                for (int ks = 0; ks < 4; ++ks)  { KSTEP(ap, ap + 16 * Dq, bp); ap += 32; bp += 2048; }
                ap = bufA + (size_t)(t & 1) * BH
                   + (size_t)(rowbase + jj) * Hq + kb * 8;
#pragma unroll 2
                for (int ks = 0; ks < 32; ++ks) { KSTEP(ap, ap + 16 * Hq, bp); ap += 32; bp += 2048; }
            }
        }

        // elementwise cell update + h write (layer1 for t>=0, layer0 for t<255)
        if (isL1 ? (t >= 0) : (t < 255)) {
            _Float16* hb = isL1 ? (bufB + (size_t)(t & 1) * BH)
                                : (bufA + (size_t)((t + 1) & 1) * BH);
#pragma unroll
            for (int mf = 0; mf < 2; ++mf) {
#pragma unroll
                for (int r = 0; r < 4; ++r) {
                    float gi = acc[mf][0][r] + bias[0];
                    float gf = acc[mf][1][r] + bias[1];
                    float gg = acc[mf][2][r] + bias[2];
                    float go = acc[mf][3][r] + bias[3];
                    float ii = 1.f / (1.f + expf(-gi));
                    float ff = 1.f / (1.f + expf(-gf));
                    float gt = tanhf(gg);
                    float oo = 1.f / (1.f + expf(-go));
                    float cn = ff * cc[mf][r] + ii * gt;
                    cc[mf][r] = cn;
                    float hn = oo * tanhf(cn);
                    int row = rowbase + mf * 16 + kb * 4 + r;
                    hb[(size_t)row * Hq + jbase + jj] = (_Float16)hn;
                    if (isL1 && t == 255)
                        hbF[(size_t)row * Hq + jbase + jj] = hn;
                }
            }
        }

        gridbar(cnt, gen, (unsigned)(t + 2));
    }

    // final: out[b][o] = b_out[o] + sum_k hbF[b][k] * Wout[o][k]   (fp32)
    int gid = bid * 256 + tid;
    if (gid < Bq * 128) {
        int b = gid >> 7, o = gid & 127;
        const floatx4* hr = (const floatx4*)(hbF + (size_t)b * Hq);
        const floatx4* wr = (const floatx4*)(Wout + (size_t)o * Hq);
        float s = bout[o];
#pragma unroll 4
        for (int k = 0; k < Hq / 4; ++k) {
            floatx4 hv = hr[k], wv = wr[k];
            s += hv[0] * wv[0] + hv[1] * wv[1] + hv[2] * wv[2] + hv[3] * wv[3];
        }
        out[gid] = s;
    }
}

// ---------------------------------------------------------------------------
extern "C" void kernel_launch(void* const* d_in, const int* in_sizes, int n_in,
                              void* d_out, int out_size, void* d_ws, size_t ws_size,
                              hipStream_t stream)
{
    (void)in_sizes; (void)n_in;
    float* out = (float*)d_out;

    if (ws_size < (size_t)REQ_WS) {
        // Diagnostic path: not enough scratch. Report ws_size (in MB, negated)
        // through d_out so the absmax value in the bench reveals it.
        float v = -(float)(ws_size >> 20);
        hipLaunchKernelGGL(ws_sentinel_kernel, dim3((out_size + 255) / 256), dim3(256),
                           0, stream, out, out_size, v);
        return;
    }

    const float* x    = (const float*)d_in[0];
    const float* h0   = (const float*)d_in[1];
    const float* c0   = (const float*)d_in[2];
    const float* Wih0 = (const float*)d_in[3];
    const float* Whh0 = (const float*)d_in[4];
    const float* bih0 = (const float*)d_in[5];
    const float* bhh0 = (const float*)d_in[6];
    const float* Wih1 = (const float*)d_in[7];
    const float* Whh1 = (const float*)d_in[8];
    const float* bih1 = (const float*)d_in[9];
    const float* bhh1 = (const float*)d_in[10];
    const float* Wout = (const float*)d_in[11];
    const float* bout = (const float*)d_in[12];

    char* ws = (char*)d_ws;
    _Float16* w1p  = (_Float16*)(ws + OFF_W1);
    _Float16* w0p  = (_Float16*)(ws + OFF_W0);
    _Float16* xh   = (_Float16*)(ws + OFF_XH);
    _Float16* bufA = (_Float16*)(ws + OFF_BA);
    _Float16* bufB = (_Float16*)(ws + OFF_BB);
    float*    hbF  = (float*)   (ws + OFF_HF);
    unsigned* sync = (unsigned*)(ws + OFF_SY);

    // prep: pack weights/x to fp16 fragment order, init h buffers, reset barrier
    long long total = N_W1 + N_W0 + N_XH + N_H;   // 21,757,952 = 84992*256
    hipLaunchKernelGGL(prep_kernel, dim3((unsigned)(total / 256)), dim3(256), 0, stream,
                       x, h0, Wih0, Whh0, Wih1, Whh1, w1p, w0p, xh, bufA, bufB, sync);

    // Plain (non-cooperative) launch: 256 blocks x 4 waves = 1024 waves vs
    // 8192 wave slots -> all blocks resident before any completes, so the
    // device-scope barrier is safe without the cooperative API.
    hipLaunchKernelGGL(lstm_main, dim3(256), dim3(256), 0, stream,
                       w1p, w0p, xh, bufA, bufB, hbF, c0,
                       bih0, bhh0, bih1, bhh1, Wout, bout, out, sync);
}

// Round 4
// 12370.346 us; speedup vs baseline: 1.0670x; 1.0670x over previous
//
#include <hip/hip_runtime.h>
#include <hip/hip_fp16.h>

// ---------------------------------------------------------------------------
// 2-layer LSTM (B=256, T=256, D=128, H=1024) + final Linear(H->128).
// Persistent kernel (plain launch, 256 blocks <= 256 CUs -> co-residency
// capacity-guaranteed), one phase per timestep, device-scope grid barrier.
// fp16 MFMA (16x16x32), fp32 accumulation/elementwise.
//
// R4 redesign: WEIGHTS LIVE IN LDS (time-invariant, loaded once).
//   - 128 L1-blocks: 8 j-cols x 4 gates x K=2048  -> 128 KB LDS
//   - 128 L0-blocks: 8 j-cols x 4 gates x K=1152  ->  72 KB LDS
//   Gate-pair N-frag packing: frag0={i,f}, frag1={g,o}; lanes jj<8 hold
//   {i,g}, jj>=8 hold {f,o} for j=jj&7 -> elementwise via 2x shfl_xor(8).
// Phase t: L1-blocks: gates1(t) = h_a(t)@Wih1^T + h_b(t-1)@Whh1^T -> h_b(t)
//          L0-blocks: gates0(t+1) = x(t+1)@Wih0^T + h_a(t)@Whh0^T -> h_a(t+1)
// Cell states stay in registers for the whole kernel.
// ---------------------------------------------------------------------------

#define Bq 256
#define Hq 1024

typedef _Float16 half8 __attribute__((ext_vector_type(8)));
typedef float    floatx4 __attribute__((ext_vector_type(4)));

#define N_W1 8388608LL   // 128 cb * 65536  ([ks64][kb4][n2][jj16][e8])
#define N_W0 4718592LL   // 128 cb * 36864  ([ks36][kb4][n2][jj16][e8])
#define N_XH 8388608LL   // T*B*D
#define N_H  262144LL    // B*H
#define BH   262144

// ws byte offsets
#define OFF_W1 0LL
#define OFF_W0 16777216LL
#define OFF_XH 26214400LL
#define OFF_BA 42991616LL
#define OFF_BB 44040192LL
#define OFF_HF 45088768LL
#define OFF_SY 46137344LL
#define REQ_WS 46137472LL   // OFF_SY + 128

// ---------------------------------------------------------------------------
__global__ void ws_sentinel_kernel(float* __restrict__ out, int n, float v)
{
    int i = blockIdx.x * blockDim.x + threadIdx.x;
    if (i < n) out[i] = v;
}

// ---------------------------------------------------------------------------
__global__ void prep_kernel(const float* __restrict__ x, const float* __restrict__ h0,
                            const float* __restrict__ Wih0, const float* __restrict__ Whh0,
                            const float* __restrict__ Wih1, const float* __restrict__ Whh1,
                            _Float16* __restrict__ w1p, _Float16* __restrict__ w0p,
                            _Float16* __restrict__ xh,
                            _Float16* __restrict__ bufA, _Float16* __restrict__ bufB,
                            unsigned* __restrict__ sync)
{
    long long gid = (long long)blockIdx.x * blockDim.x + threadIdx.x;
    if (gid == 0) { sync[0] = 0u; sync[1] = 0u; }

    if (gid < N_W1) {
        // [cb][ks][kb][n][jj][e]; gate-col row = (2n + jj>>3)*1024 + cb*8 + (jj&7)
        long long i = gid;
        int e  = (int)(i & 7);
        int jj = (int)((i >> 3) & 15);
        int n  = (int)((i >> 7) & 1);
        int kb = (int)((i >> 8) & 3);
        int ks = (int)((i >> 10) & 63);
        int cb = (int)(i >> 16);
        int row = (2 * n + (jj >> 3)) * 1024 + cb * 8 + (jj & 7);
        int k = ks * 32 + kb * 8 + e;
        float v = (k < 1024) ? Wih1[(size_t)row * 1024 + k]
                             : Whh1[(size_t)row * 1024 + (k - 1024)];
        w1p[i] = (_Float16)v;
    } else if (gid < N_W1 + N_W0) {
        long long i = gid - N_W1;
        int cb = (int)(i / 36864LL);
        int r  = (int)(i - (long long)cb * 36864LL);
        int ks = r >> 10;
        int kb = (r >> 8) & 3;
        int n  = (r >> 7) & 1;
        int jj = (r >> 3) & 15;
        int e  = r & 7;
        int row = (2 * n + (jj >> 3)) * 1024 + cb * 8 + (jj & 7);
        int k = ks * 32 + kb * 8 + e;
        float v = (k < 128) ? Wih0[(size_t)row * 128 + k]
                            : Whh0[(size_t)row * 1024 + (k - 128)];
        w0p[i] = (_Float16)v;
    } else if (gid < N_W1 + N_W0 + N_XH) {
        long long i = gid - N_W1 - N_W0;
        // xh[t][b][d] = x[b][t][d]
        int d = (int)(i & 127);
        int b = (int)((i >> 7) & 255);
        int t = (int)(i >> 15);
        xh[i] = (_Float16)x[((size_t)b * 256 + t) * 128 + d];
    } else if (gid < N_W1 + N_W0 + N_XH + N_H) {
        long long i = gid - N_W1 - N_W0 - N_XH;
        _Float16 v = (_Float16)h0[i];
        bufA[BH + i] = v;   // h_a(-1) parity 1
        bufB[BH + i] = v;   // h_b(-1) parity 1
    }
}

// ---------------------------------------------------------------------------
__device__ __forceinline__ void gridbar(unsigned* cnt, unsigned* gen, unsigned target)
{
    __syncthreads();
    if (threadIdx.x == 0) {
        unsigned prev = __hip_atomic_fetch_add(cnt, 1u, __ATOMIC_ACQ_REL,
                                               __HIP_MEMORY_SCOPE_AGENT);
        if (prev == gridDim.x - 1u) {
            __hip_atomic_store(cnt, 0u, __ATOMIC_RELAXED, __HIP_MEMORY_SCOPE_AGENT);
            __hip_atomic_store(gen, target, __ATOMIC_RELEASE, __HIP_MEMORY_SCOPE_AGENT);
        } else {
            int guard = 0;
            while (__hip_atomic_load(gen, __ATOMIC_RELAXED, __HIP_MEMORY_SCOPE_AGENT) < target) {
                __builtin_amdgcn_s_sleep(1);
                if (++guard > (1 << 21)) break;
            }
            (void)__hip_atomic_load(gen, __ATOMIC_ACQUIRE, __HIP_MEMORY_SCOPE_AGENT);
        }
    }
    __syncthreads();
}

#define MFMA16(A, Bv, C) __builtin_amdgcn_mfma_f32_16x16x32_f16((A), (Bv), (C), 0, 0, 0)

// one k-step (K=32): 2 A-frags (global), 2 B-frags (LDS), 4 MFMAs
#define KS1(AP_, MF1OFF_) do {                                      \
    half8 a0 = *(const half8*)(AP_);                                \
    half8 a1 = *(const half8*)((AP_) + (MF1OFF_));                  \
    half8 b0 = *(const half8*)(bp);                                 \
    half8 b1 = *(const half8*)(bp + 128);                           \
    acc[0][0] = MFMA16(a0, b0, acc[0][0]);                          \
    acc[0][1] = MFMA16(a0, b1, acc[0][1]);                          \
    acc[1][0] = MFMA16(a1, b0, acc[1][0]);                          \
    acc[1][1] = MFMA16(a1, b1, acc[1][1]);                          \
} while (0)

__global__ void __launch_bounds__(512)
lstm_main(const _Float16* __restrict__ w1p, const _Float16* __restrict__ w0p,
          const _Float16* __restrict__ xh,
          _Float16* __restrict__ bufA, _Float16* __restrict__ bufB,
          float* __restrict__ hbF,
          const float* __restrict__ c0,
          const float* __restrict__ bih0, const float* __restrict__ bhh0,
          const float* __restrict__ bih1, const float* __restrict__ bhh1,
          const float* __restrict__ Wout, const float* __restrict__ bout,
          float* __restrict__ out, unsigned* __restrict__ sync)
{
    __shared__ _Float16 wlds[65536];   // 128 KiB

    const int tid  = threadIdx.x;
    const int lane = tid & 63;
    const int w    = tid >> 6;           // 0..7
    const int bid  = blockIdx.x;
    const int xcd  = bid & 7;
    const int slot = bid >> 3;           // 0..31
    const int isL1 = ((slot & 1) == 0);  // 16 L1 + 16 L0 blocks per XCD
    const int cb   = xcd * 16 + (slot >> 1);   // 0..127 column-block id
    const int jbase = cb * 8;
    const int jj = lane & 15;
    const int kb = lane >> 4;            // 0..3
    const int jh = jj & 7;
    const int lo = (jj < 8);
    const int rowbase = w * 32;          // wave's 32 batch rows

    unsigned* cnt = sync;
    unsigned* gen = sync + 1;

    // ---- load this block's weights into LDS (once) ----
    {
        const _Float16* src = isL1 ? (w1p + (size_t)cb * 65536)
                                   : (w0p + (size_t)cb * 36864);
        const int nch = isL1 ? 8192 : 4608;   // 16B chunks
        for (int i = tid; i < nch; i += 512)
            *(half8*)&wlds[(size_t)i * 8] = *(const half8*)&src[(size_t)i * 8];
    }
    __syncthreads();

    // ---- biases + cell-state init ----
    const float* bi  = isL1 ? bih1 : bih0;
    const float* bhp = isL1 ? bhh1 : bhh0;
    float bias[4];
#pragma unroll
    for (int g = 0; g < 4; ++g)
        bias[g] = bi[g * 1024 + jbase + jh] + bhp[g * 1024 + jbase + jh];

    float cc[2][4];
#pragma unroll
    for (int mf = 0; mf < 2; ++mf)
#pragma unroll
        for (int r = 0; r < 4; ++r)
            cc[mf][r] = c0[(size_t)(rowbase + mf * 16 + kb * 4 + r) * Hq + jbase + jh];

    floatx4 acc[2][2];

    for (int t = -1; t <= 255; ++t) {
        const int active = isL1 ? (t >= 0) : (t < 255);
        if (active) {
#pragma unroll
            for (int mf = 0; mf < 2; ++mf)
#pragma unroll
                for (int n = 0; n < 2; ++n)
                    acc[mf][n] = (floatx4){0.f, 0.f, 0.f, 0.f};

            const _Float16* bp = wlds + kb * 256 + jj * 8;

            if (isL1) {
                // part 1: h_a(t)  (ks 0..31)
                const _Float16* ap = bufA + (size_t)(t & 1) * BH
                                   + (size_t)(rowbase + jj) * Hq + kb * 8;
#pragma unroll 4
                for (int ks = 0; ks < 32; ++ks) { KS1(ap, 16 * Hq); ap += 32; bp += 1024; }
                // part 2: h_b(t-1)  (ks 32..63)
                ap = bufB + (size_t)((t + 1) & 1) * BH
                   + (size_t)(rowbase + jj) * Hq + kb * 8;
#pragma unroll 4
                for (int ks = 0; ks < 32; ++ks) { KS1(ap, 16 * Hq); ap += 32; bp += 1024; }
            } else {
                // part 1: x(t+1)  (ks 0..3, K=128 rows)
                const _Float16* ap = xh + (size_t)(t + 1) * (Bq * 128)
                                   + (size_t)(rowbase + jj) * 128 + kb * 8;
#pragma unroll
                for (int ks = 0; ks < 4; ++ks)  { KS1(ap, 16 * 128); ap += 32; bp += 1024; }
                // part 2: h_a(t)  (ks 4..35)
                ap = bufA + (size_t)(t & 1) * BH
                   + (size_t)(rowbase + jj) * Hq + kb * 8;
#pragma unroll 4
                for (int ks = 0; ks < 32; ++ks) { KS1(ap, 16 * Hq); ap += 32; bp += 1024; }
            }

            // ---- elementwise: gate-pair exchange + cell update + h store ----
            _Float16* hb = isL1 ? (bufB + (size_t)(t & 1) * BH)
                                : (bufA + (size_t)((t + 1) & 1) * BH);
#pragma unroll
            for (int mf = 0; mf < 2; ++mf) {
#pragma unroll
                for (int r = 0; r < 4; ++r) {
                    float o0 = acc[mf][0][r];       // lo: i, hi: f
                    float o1 = acc[mf][1][r];       // lo: g, hi: o
                    float p0 = __shfl_xor(o0, 8);
                    float p1 = __shfl_xor(o1, 8);
                    float gi = (lo ? o0 : p0) + bias[0];
                    float gf = (lo ? p0 : o0) + bias[1];
                    float gg = (lo ? o1 : p1) + bias[2];
                    float go = (lo ? p1 : o1) + bias[3];
                    float ii = 1.f / (1.f + expf(-gi));
                    float ff = 1.f / (1.f + expf(-gf));
                    float gt = tanhf(gg);
                    float oo = 1.f / (1.f + expf(-go));
                    float cn = ff * cc[mf][r] + ii * gt;
                    cc[mf][r] = cn;
                    float hn = oo * tanhf(cn);
                    if (lo) {
                        int row = rowbase + mf * 16 + kb * 4 + r;
                        hb[(size_t)row * Hq + jbase + jh] = (_Float16)hn;
                        if (isL1 && t == 255)
                            hbF[(size_t)row * Hq + jbase + jh] = hn;
                    }
                }
            }
        }

        gridbar(cnt, gen, (unsigned)(t + 2));
    }

    // ---- final: out[b][o] = b_out[o] + sum_k hbF[b][k] * Wout[o][k] ----
    int gid = bid * 512 + tid;
    if (gid < Bq * 128) {
        int b = gid >> 7, o = gid & 127;
        const floatx4* hr = (const floatx4*)(hbF + (size_t)b * Hq);
        const floatx4* wr = (const floatx4*)(Wout + (size_t)o * Hq);
        float s = bout[o];
#pragma unroll 4
        for (int k = 0; k < Hq / 4; ++k) {
            floatx4 hv = hr[k], wv = wr[k];
            s += hv[0] * wv[0] + hv[1] * wv[1] + hv[2] * wv[2] + hv[3] * wv[3];
        }
        out[gid] = s;
    }
}

// ---------------------------------------------------------------------------
extern "C" void kernel_launch(void* const* d_in, const int* in_sizes, int n_in,
                              void* d_out, int out_size, void* d_ws, size_t ws_size,
                              hipStream_t stream)
{
    (void)in_sizes; (void)n_in;
    float* out = (float*)d_out;

    if (ws_size < (size_t)REQ_WS) {
        float v = -(float)(ws_size >> 20);
        hipLaunchKernelGGL(ws_sentinel_kernel, dim3((out_size + 255) / 256), dim3(256),
                           0, stream, out, out_size, v);
        return;
    }

    const float* x    = (const float*)d_in[0];
    const float* h0   = (const float*)d_in[1];
    const float* c0   = (const float*)d_in[2];
    const float* Wih0 = (const float*)d_in[3];
    const float* Whh0 = (const float*)d_in[4];
    const float* bih0 = (const float*)d_in[5];
    const float* bhh0 = (const float*)d_in[6];
    const float* Wih1 = (const float*)d_in[7];
    const float* Whh1 = (const float*)d_in[8];
    const float* bih1 = (const float*)d_in[9];
    const float* bhh1 = (const float*)d_in[10];
    const float* Wout = (const float*)d_in[11];
    const float* bout = (const float*)d_in[12];

    char* ws = (char*)d_ws;
    _Float16* w1p  = (_Float16*)(ws + OFF_W1);
    _Float16* w0p  = (_Float16*)(ws + OFF_W0);
    _Float16* xh   = (_Float16*)(ws + OFF_XH);
    _Float16* bufA = (_Float16*)(ws + OFF_BA);
    _Float16* bufB = (_Float16*)(ws + OFF_BB);
    float*    hbF  = (float*)   (ws + OFF_HF);
    unsigned* sync = (unsigned*)(ws + OFF_SY);

    long long total = N_W1 + N_W0 + N_XH + N_H;   // 21,757,952 = 84992*256
    hipLaunchKernelGGL(prep_kernel, dim3((unsigned)(total / 256)), dim3(256), 0, stream,
                       x, h0, Wih0, Whh0, Wih1, Whh1, w1p, w0p, xh, bufA, bufB, sync);

    hipLaunchKernelGGL(lstm_main, dim3(256), dim3(512), 0, stream,
                       w1p, w0p, xh, bufA, bufB, hbF, c0,
                       bih0, bhh0, bih1, bhh1, Wout, bout, out, sync);
}

// Round 7
// 9781.278 us; speedup vs baseline: 1.3495x; 1.2647x over previous
//
#include <hip/hip_runtime.h>
#include <hip/hip_fp16.h>

// ---------------------------------------------------------------------------
// 2-layer LSTM (B=256, T=256, D=128, H=1024) + final Linear(H->128).
// Persistent kernel, one phase per timestep, device-scope grid barrier.
// fp16 MFMA (16x16x32), fp32 accumulation/elementwise. Weights in LDS.
//
// R5 (resubmit R7): fence-free data plane. All cross-block h/c traffic uses
// RELAXED agent-scope atomic stores (sc1 write-through -> L2 never dirty), so
// the barrier needs NO release fence (no buffer_wbl2). Freshness for cached
// reads via ONE acquire fence (buffer_inv) per CU per phase. Tree barrier
// (8 groups x 32) with monotonic counters, all relaxed atomics.
// ---------------------------------------------------------------------------

#define Bq 256
#define Hq 1024

typedef _Float16 half8 __attribute__((ext_vector_type(8)));
typedef float    floatx4 __attribute__((ext_vector_type(4)));

#define N_W1 8388608LL   // 128 cb * 65536  ([ks64][kb4][n2][jj16][e8])
#define N_W0 4718592LL   // 128 cb * 36864  ([ks36][kb4][n2][jj16][e8])
#define N_XH 8388608LL   // T*B*D
#define N_H  262144LL    // B*H
#define BH   262144

// ws byte offsets
#define OFF_W1 0LL
#define OFF_W0 16777216LL
#define OFF_XH 26214400LL
#define OFF_BA 42991616LL
#define OFF_BB 44040192LL
#define OFF_HF 45088768LL
#define OFF_SY 46137344LL
#define REQ_WS 46139392LL   // OFF_SY + 2048

// ---------------------------------------------------------------------------
__global__ void ws_sentinel_kernel(float* __restrict__ out, int n, float v)
{
    int i = blockIdx.x * blockDim.x + threadIdx.x;
    if (i < n) out[i] = v;
}

// ---------------------------------------------------------------------------
__global__ void prep_kernel(const float* __restrict__ x, const float* __restrict__ h0,
                            const float* __restrict__ Wih0, const float* __restrict__ Whh0,
                            const float* __restrict__ Wih1, const float* __restrict__ Whh1,
                            _Float16* __restrict__ w1p, _Float16* __restrict__ w0p,
                            _Float16* __restrict__ xh,
                            _Float16* __restrict__ bufA, _Float16* __restrict__ bufB,
                            unsigned* __restrict__ sync)
{
    long long gid = (long long)blockIdx.x * blockDim.x + threadIdx.x;
    if (gid < 512) sync[gid] = 0u;   // gen/root/group counters (monotonic)

    if (gid < N_W1) {
        // [cb][ks][kb][n][jj][e]; gate-col row = (2n + jj>>3)*1024 + cb*8 + (jj&7)
        long long i = gid;
        int e  = (int)(i & 7);
        int jj = (int)((i >> 3) & 15);
        int n  = (int)((i >> 7) & 1);
        int kb = (int)((i >> 8) & 3);
        int ks = (int)((i >> 10) & 63);
        int cb = (int)(i >> 16);
        int row = (2 * n + (jj >> 3)) * 1024 + cb * 8 + (jj & 7);
        int k = ks * 32 + kb * 8 + e;
        float v = (k < 1024) ? Wih1[(size_t)row * 1024 + k]
                             : Whh1[(size_t)row * 1024 + (k - 1024)];
        w1p[i] = (_Float16)v;
    } else if (gid < N_W1 + N_W0) {
        long long i = gid - N_W1;
        int cb = (int)(i / 36864LL);
        int r  = (int)(i - (long long)cb * 36864LL);
        int ks = r >> 10;
        int kb = (r >> 8) & 3;
        int n  = (r >> 7) & 1;
        int jj = (r >> 3) & 15;
        int e  = r & 7;
        int row = (2 * n + (jj >> 3)) * 1024 + cb * 8 + (jj & 7);
        int k = ks * 32 + kb * 8 + e;
        float v = (k < 128) ? Wih0[(size_t)row * 128 + k]
                            : Whh0[(size_t)row * 1024 + (k - 128)];
        w0p[i] = (_Float16)v;
    } else if (gid < N_W1 + N_W0 + N_XH) {
        long long i = gid - N_W1 - N_W0;
        // xh[t][b][d] = x[b][t][d]
        int d = (int)(i & 127);
        int b = (int)((i >> 7) & 255);
        int t = (int)(i >> 15);
        xh[i] = (_Float16)x[((size_t)b * 256 + t) * 128 + d];
    } else if (gid < N_W1 + N_W0 + N_XH + N_H) {
        long long i = gid - N_W1 - N_W0 - N_XH;
        _Float16 v = (_Float16)h0[i];
        bufA[BH + i] = v;   // h_a(-1) parity 1
        bufB[BH + i] = v;   // h_b(-1) parity 1
    }
}

// ---------------------------------------------------------------------------
// Fence-free tree barrier. Preconditions: all cross-block data written with
// relaxed agent-scope atomic stores (sc1, write-through); callers' stores
// drained via s_waitcnt(0) before arrival. Monotonic counters, no resets.
// sync layout (uints): [0]=gen  [16]=root  [32+g*32]=group g (g=0..7)
__device__ __forceinline__ void gridbar(unsigned* sync, int bid, unsigned target)
{
    __builtin_amdgcn_s_waitcnt(0);     // own stores complete at coherence point
    __syncthreads();                   // whole block's stores complete
    if (threadIdx.x == 0) {
        unsigned* gen  = sync;
        unsigned* root = sync + 16;
        unsigned* grp  = sync + 32 + (bid & 7) * 32;
        unsigned prev = __hip_atomic_fetch_add(grp, 1u, __ATOMIC_RELAXED,
                                               __HIP_MEMORY_SCOPE_AGENT);
        if (prev == 32u * target - 1u) {           // last of my 32-block group
            unsigned prevr = __hip_atomic_fetch_add(root, 1u, __ATOMIC_RELAXED,
                                                    __HIP_MEMORY_SCOPE_AGENT);
            if (prevr == 8u * target - 1u)         // last group
                __hip_atomic_store(gen, target, __ATOMIC_RELAXED,
                                   __HIP_MEMORY_SCOPE_AGENT);
        }
        int guard = 0;
        while (__hip_atomic_load(gen, __ATOMIC_RELAXED,
                                 __HIP_MEMORY_SCOPE_AGENT) < target) {
            __builtin_amdgcn_s_sleep(1);
            if (++guard > (1 << 18)) break;        // safety: wrong, not wedged
        }
    }
    __syncthreads();
    if (threadIdx.x < 64)                           // one inv per CU (L1+L2)
        __builtin_amdgcn_fence(__ATOMIC_ACQUIRE, "agent");
    __syncthreads();
}

#define MFMA16(A, Bv, C) __builtin_amdgcn_mfma_f32_16x16x32_f16((A), (Bv), (C), 0, 0, 0)

// one k-step (K=32): 2 A-frags (global), 2 B-frags (LDS), 4 MFMAs
#define KS1(AP_, MF1OFF_) do {                                      \
    half8 a0 = *(const half8*)(AP_);                                \
    half8 a1 = *(const half8*)((AP_) + (MF1OFF_));                  \
    half8 b0 = *(const half8*)(bp);                                 \
    half8 b1 = *(const half8*)(bp + 128);                           \
    acc[0][0] = MFMA16(a0, b0, acc[0][0]);                          \
    acc[0][1] = MFMA16(a0, b1, acc[0][1]);                          \
    acc[1][0] = MFMA16(a1, b0, acc[1][0]);                          \
    acc[1][1] = MFMA16(a1, b1, acc[1][1]);                          \
} while (0)

__global__ void __launch_bounds__(512)
lstm_main(const _Float16* __restrict__ w1p, const _Float16* __restrict__ w0p,
          const _Float16* __restrict__ xh,
          _Float16* __restrict__ bufA, _Float16* __restrict__ bufB,
          float* __restrict__ hbF,
          const float* __restrict__ c0,
          const float* __restrict__ bih0, const float* __restrict__ bhh0,
          const float* __restrict__ bih1, const float* __restrict__ bhh1,
          const float* __restrict__ Wout, const float* __restrict__ bout,
          float* __restrict__ out, unsigned* __restrict__ sync)
{
    __shared__ _Float16 wlds[65536];   // 128 KiB

    const int tid  = threadIdx.x;
    const int lane = tid & 63;
    const int w    = tid >> 6;           // 0..7
    const int bid  = blockIdx.x;
    const int xcd  = bid & 7;
    const int slot = bid >> 3;           // 0..31
    const int isL1 = ((slot & 1) == 0);  // 16 L1 + 16 L0 blocks per XCD
    const int cb   = xcd * 16 + (slot >> 1);   // 0..127 column-block id
    const int jbase = cb * 8;
    const int jj = lane & 15;
    const int kb = lane >> 4;            // 0..3
    const int jh = jj & 7;
    const int lo = (jj < 8);
    const int rowbase = w * 32;          // wave's 32 batch rows

    // ---- load this block's weights into LDS (once) ----
    {
        const _Float16* src = isL1 ? (w1p + (size_t)cb * 65536)
                                   : (w0p + (size_t)cb * 36864);
        const int nch = isL1 ? 8192 : 4608;   // 16B chunks
        for (int i = tid; i < nch; i += 512)
            *(half8*)&wlds[(size_t)i * 8] = *(const half8*)&src[(size_t)i * 8];
    }
    __syncthreads();

    // ---- biases + cell-state init ----
    const float* bi  = isL1 ? bih1 : bih0;
    const float* bhp = isL1 ? bhh1 : bhh0;
    float bias[4];
#pragma unroll
    for (int g = 0; g < 4; ++g)
        bias[g] = bi[g * 1024 + jbase + jh] + bhp[g * 1024 + jbase + jh];

    float cc[2][4];
#pragma unroll
    for (int mf = 0; mf < 2; ++mf)
#pragma unroll
        for (int r = 0; r < 4; ++r)
            cc[mf][r] = c0[(size_t)(rowbase + mf * 16 + kb * 4 + r) * Hq + jbase + jh];

    floatx4 acc[2][2];

    for (int t = -1; t <= 255; ++t) {
        const int active = isL1 ? (t >= 0) : (t < 255);
        if (active) {
#pragma unroll
            for (int mf = 0; mf < 2; ++mf)
#pragma unroll
                for (int n = 0; n < 2; ++n)
                    acc[mf][n] = (floatx4){0.f, 0.f, 0.f, 0.f};

            const _Float16* bp = wlds + kb * 256 + jj * 8;

            if (isL1) {
                // part 1: h_a(t)  (ks 0..31)
                const _Float16* ap = bufA + (size_t)(t & 1) * BH
                                   + (size_t)(rowbase + jj) * Hq + kb * 8;
#pragma unroll 4
                for (int ks = 0; ks < 32; ++ks) { KS1(ap, 16 * Hq); ap += 32; bp += 1024; }
                // part 2: h_b(t-1)  (ks 32..63)
                ap = bufB + (size_t)((t + 1) & 1) * BH
                   + (size_t)(rowbase + jj) * Hq + kb * 8;
#pragma unroll 4
                for (int ks = 0; ks < 32; ++ks) { KS1(ap, 16 * Hq); ap += 32; bp += 1024; }
            } else {
                // part 1: x(t+1)  (ks 0..3, K=128 rows)
                const _Float16* ap = xh + (size_t)(t + 1) * (Bq * 128)
                                   + (size_t)(rowbase + jj) * 128 + kb * 8;
#pragma unroll
                for (int ks = 0; ks < 4; ++ks)  { KS1(ap, 16 * 128); ap += 32; bp += 1024; }
                // part 2: h_a(t)  (ks 4..35)
                ap = bufA + (size_t)(t & 1) * BH
                   + (size_t)(rowbase + jj) * Hq + kb * 8;
#pragma unroll 4
                for (int ks = 0; ks < 32; ++ks) { KS1(ap, 16 * Hq); ap += 32; bp += 1024; }
            }

            // ---- elementwise: gate-pair exchange + cell update + h store ----
            // h stores: fp16 pairs packed to 4B words, RELAXED agent atomics
            // (sc1 write-through -> no dirty L2 anywhere in the main loop).
            _Float16* hb = isL1 ? (bufB + (size_t)(t & 1) * BH)
                                : (bufA + (size_t)((t + 1) & 1) * BH);
            unsigned* hb32 = (unsigned*)hb;
#pragma unroll
            for (int mf = 0; mf < 2; ++mf) {
#pragma unroll
                for (int r = 0; r < 4; ++r) {
                    float o0 = acc[mf][0][r];       // lo: i, hi: f
                    float o1 = acc[mf][1][r];       // lo: g, hi: o
                    float p0 = __shfl_xor(o0, 8);
                    float p1 = __shfl_xor(o1, 8);
                    float gi = (lo ? o0 : p0) + bias[0];
                    float gf = (lo ? p0 : o0) + bias[1];
                    float gg = (lo ? o1 : p1) + bias[2];
                    float go = (lo ? p1 : o1) + bias[3];
                    float ii = 1.f / (1.f + expf(-gi));
                    float ff = 1.f / (1.f + expf(-gf));
                    float gt = tanhf(gg);
                    float oo = 1.f / (1.f + expf(-go));
                    float cn = ff * cc[mf][r] + ii * gt;
                    cc[mf][r] = cn;
                    float hn = oo * tanhf(cn);

                    union { _Float16 f; unsigned short u; } cv;
                    cv.f = (_Float16)hn;
                    int prt = __shfl_xor((int)cv.u, 1);   // neighbor j^1's bits
                    int row = rowbase + mf * 16 + kb * 4 + r;
                    if (lo && ((jh & 1) == 0)) {
                        unsigned word = (unsigned)cv.u | ((unsigned)prt << 16);
                        __hip_atomic_store(hb32 + (((size_t)row * Hq + jbase + jh) >> 1),
                                           word, __ATOMIC_RELAXED,
                                           __HIP_MEMORY_SCOPE_AGENT);
                    }
                    if (lo && isL1 && t == 255)
                        __hip_atomic_store(hbF + (size_t)row * Hq + jbase + jh,
                                           hn, __ATOMIC_RELAXED,
                                           __HIP_MEMORY_SCOPE_AGENT);
                }
            }
        }

        gridbar(sync, bid, (unsigned)(t + 2));
    }

    // ---- final: out[b][o] = b_out[o] + sum_k hbF[b][k] * Wout[o][k] ----
    int gid = bid * 512 + tid;
    if (gid < Bq * 128) {
        int b = gid >> 7, o = gid & 127;
        const floatx4* hr = (const floatx4*)(hbF + (size_t)b * Hq);
        const floatx4* wr = (const floatx4*)(Wout + (size_t)o * Hq);
        float s = bout[o];
#pragma unroll 4
        for (int k = 0; k < Hq / 4; ++k) {
            floatx4 hv = hr[k], wv = wr[k];
            s += hv[0] * wv[0] + hv[1] * wv[1] + hv[2] * wv[2] + hv[3] * wv[3];
        }
        out[gid] = s;
    }
}

// ---------------------------------------------------------------------------
extern "C" void kernel_launch(void* const* d_in, const int* in_sizes, int n_in,
                              void* d_out, int out_size, void* d_ws, size_t ws_size,
                              hipStream_t stream)
{
    (void)in_sizes; (void)n_in;
    float* out = (float*)d_out;

    if (ws_size < (size_t)REQ_WS) {
        float v = -(float)(ws_size >> 20);
        hipLaunchKernelGGL(ws_sentinel_kernel, dim3((out_size + 255) / 256), dim3(256),
                           0, stream, out, out_size, v);
        return;
    }

    const float* x    = (const float*)d_in[0];
    const float* h0   = (const float*)d_in[1];
    const float* c0   = (const float*)d_in[2];
    const float* Wih0 = (const float*)d_in[3];
    const float* Whh0 = (const float*)d_in[4];
    const float* bih0 = (const float*)d_in[5];
    const float* bhh0 = (const float*)d_in[6];
    const float* Wih1 = (const float*)d_in[7];
    const float* Whh1 = (const float*)d_in[8];
    const float* bih1 = (const float*)d_in[9];
    const float* bhh1 = (const float*)d_in[10];
    const float* Wout = (const float*)d_in[11];
    const float* bout = (const float*)d_in[12];

    char* ws = (char*)d_ws;
    _Float16* w1p  = (_Float16*)(ws + OFF_W1);
    _Float16* w0p  = (_Float16*)(ws + OFF_W0);
    _Float16* xh   = (_Float16*)(ws + OFF_XH);
    _Float16* bufA = (_Float16*)(ws + OFF_BA);
    _Float16* bufB = (_Float16*)(ws + OFF_BB);
    float*    hbF  = (float*)   (ws + OFF_HF);
    unsigned* sync = (unsigned*)(ws + OFF_SY);

    long long total = N_W1 + N_W0 + N_XH + N_H;   // 21,757,952 = 84992*256
    hipLaunchKernelGGL(prep_kernel, dim3((unsigned)(total / 256)), dim3(256), 0, stream,
                       x, h0, Wih0, Whh0, Wih1, Whh1, w1p, w0p, xh, bufA, bufB, sync);

    hipLaunchKernelGGL(lstm_main, dim3(256), dim3(512), 0, stream,
                       w1p, w0p, xh, bufA, bufB, hbF, c0,
                       bih0, bhh0, bih1, bhh1, Wout, bout, out, sync);
}